// Round 1
// baseline (2907.956 us; speedup 1.0000x reference)
//
#include <hip/hip_runtime.h>
#include <math.h>

// ---------------- problem constants ----------------
#define NN   32
#define CC   128
#define TT   400
#define VV   27
#define SS   2
#define ICC  32
#define RCC  32
#define TVV  (TT * VV)            // 10800
#define EPSF 1e-5f

static constexpr size_t CTV = (size_t)CC * TVV;      // 1,382,400
static constexpr size_t FSZ = (size_t)NN * CTV;      // 44,236,800
static constexpr size_t F4  = (size_t)NN * RCC * TVV;// 11,059,200

// ---------------- workspace layout (floats) ----------------
static constexpr size_t OFF_PE      = 0;        // 3456
static constexpr size_t OFF_WT_IN   = 4096;     // 16384   in_w^T [c][o]
static constexpr size_t OFF_WS_OUT  = 20480;    // 32768   out_w scaled [o][sc]
static constexpr size_t OFF_B_OUT   = 53248;    // 128
static constexpr size_t OFF_WT_FF   = 53376;    // 16384   ff_w^T scaled [c][o]
static constexpr size_t OFF_B_FF    = 69760;    // 128
static constexpr size_t OFF_WT_DOWN = 69888;    // 4096    down_w^T scaled [c][o]
static constexpr size_t OFF_B_DOWN  = 73984;    // 32
static constexpr size_t OFF_DWS     = 74016;    // 288     dw_w scaled
static constexpr size_t OFF_DBS     = 74304;    // 96
static constexpr size_t OFF_PWS     = 74400;    // 3072    pw_w scaled
static constexpr size_t OFF_BSUM    = 77472;    // 32
static constexpr size_t OFF_WT_BACK = 77504;    // 4096    back_w^T scaled [k][o]
static constexpr size_t OFF_B_BACK  = 81600;    // 128
static constexpr size_t OFF_ATT     = 81728;    // 46656   [n][s][u][v]
static constexpr size_t OFF_ATTP    = 128384;   // 8*46656 partial gram
static constexpr size_t OFF_BUFA    = 501760;   // FSZ   (qk, then y2)
static constexpr size_t OFF_YD      = OFF_BUFA + FSZ;  // F4
static constexpr size_t OFF_ACC     = OFF_YD + F4;     // F4
// total = 66,856,960 floats = 267.4 MB  (must be <= ws_size)

// ---------------- prep: pe table + transposed / BN-folded weights ----------------
__global__ void prep_k(const float* __restrict__ in_w,
                       const float* __restrict__ out_w, const float* __restrict__ out_b,
                       const float* __restrict__ out_bn,
                       const float* __restrict__ ff_w, const float* __restrict__ ff_b,
                       const float* __restrict__ ff_bn,
                       const float* __restrict__ down_w, const float* __restrict__ down_bn,
                       const float* __restrict__ dw_w, const float* __restrict__ dw_b,
                       const float* __restrict__ bn_a,
                       const float* __restrict__ pw_w, const float* __restrict__ bn_b,
                       const float* __restrict__ back_w, const float* __restrict__ back_bn,
                       float* __restrict__ ws)
{
  const int gid = blockIdx.x * blockDim.x + threadIdx.x;
  const int nth = gridDim.x * blockDim.x;
  const float rs = rsqrtf(1.f + EPSF);

  // positional encoding pe[c][v]
  for (int i = gid; i < CC * VV; i += nth) {
    const int c = i / VV, v = i % VV;
    const int h = c >> 1;
    const float div = expf((float)(2 * h) * (-logf(10000.f) / (float)CC));
    const float ang = (float)v * div;
    ws[OFF_PE + i] = (c & 1) ? cosf(ang) : sinf(ang);
  }
  // in_w^T  [c][o]
  for (int i = gid; i < CC * CC; i += nth) {
    const int c = i >> 7, o = i & 127;
    ws[OFF_WT_IN + i] = in_w[o * CC + c];
  }
  // out_w scaled, keep [o][sc]
  for (int i = gid; i < CC * 2 * CC; i += nth) {
    const int o = i >> 8;
    ws[OFF_WS_OUT + i] = out_w[i] * (out_bn[o] * rs);
  }
  for (int i = gid; i < CC; i += nth) {
    const float s = out_bn[i] * rs;
    ws[OFF_B_OUT + i] = s * out_b[i] + out_bn[CC + i];
  }
  // ff
  for (int i = gid; i < CC * CC; i += nth) {
    const int c = i >> 7, o = i & 127;
    ws[OFF_WT_FF + i] = ff_w[o * CC + c] * (ff_bn[o] * rs);
  }
  for (int i = gid; i < CC; i += nth) {
    const float s = ff_bn[i] * rs;
    ws[OFF_B_FF + i] = s * ff_b[i] + ff_bn[CC + i];
  }
  // down
  for (int i = gid; i < CC * RCC; i += nth) {
    const int c = i >> 5, o = i & 31;
    ws[OFF_WT_DOWN + i] = down_w[o * CC + c] * (down_bn[o] * rs);
  }
  for (int i = gid; i < RCC; i += nth) ws[OFF_B_DOWN + i] = down_bn[RCC + i];
  // depthwise (scaled by bn_a gamma)
  for (int i = gid; i < 3 * RCC * 3; i += nth) {
    const int b = i / 96, r = i % 96, c = r / 3;
    ws[OFF_DWS + i] = dw_w[i] * (bn_a[b * 64 + c] * rs);
  }
  for (int i = gid; i < 3 * RCC; i += nth) {
    const int b = i >> 5, c = i & 31;
    ws[OFF_DBS + i] = (bn_a[b * 64 + c] * rs) * dw_b[i] + bn_a[b * 64 + 32 + c];
  }
  // pointwise (scaled by bn_b gamma)
  for (int i = gid; i < 3 * RCC * RCC; i += nth) {
    const int b = i >> 10, o = (i & 1023) >> 5;
    ws[OFF_PWS + i] = pw_w[i] * (bn_b[b * 64 + o] * rs);
  }
  for (int i = gid; i < RCC; i += nth)
    ws[OFF_BSUM + i] = bn_b[32 + i] + bn_b[96 + i] + bn_b[160 + i];
  // back
  for (int i = gid; i < RCC * CC; i += nth) {
    const int k = i >> 7, o = i & 127;
    ws[OFF_WT_BACK + i] = back_w[o * RCC + k] * (back_bn[o] * rs);
  }
  for (int i = gid; i < CC; i += nth) ws[OFF_B_BACK + i] = back_bn[CC + i];
}

// ---------------- generic 1x1-conv GEMM:  Y[n][o][p] = act(res + W^T X + b) ----
// X: [n][K][TVV], wT: [k][M], per-block tile: M x 64 cols, thread tile TM x 4.
template<int M, int K, int TM, bool PE, bool RES, bool LR>
__global__ __launch_bounds__(256, 2) void gemm_k(
    const float* __restrict__ X, const float* __restrict__ wT,
    const float* __restrict__ bias, const float* __restrict__ resid,
    const float* __restrict__ pe, float* __restrict__ Y)
{
  __shared__ float Xs[32][68];        // padded (+4) to spread store banks
  __shared__ float Ws[32][M + 4];
  const int n  = blockIdx.y;
  const int p0 = blockIdx.x * 64;
  const int tid = threadIdx.x;
  const int pg = tid & 15;            // 16 col-groups * 4
  const int og = tid >> 4;            // 16 row-groups * TM

  float acc[TM][4];
#pragma unroll
  for (int i = 0; i < TM; ++i)
#pragma unroll
    for (int j = 0; j < 4; ++j) acc[i][j] = 0.f;

  const float* Xn = X + (size_t)n * K * TVV;
  const int r  = tid >> 3;            // 0..31 staging row
  const int c0 = (tid & 7) * 8;       // staging col base

  for (int k0 = 0; k0 < K; k0 += 32) {
    const float* src = Xn + (size_t)(k0 + r) * TVV;
#pragma unroll
    for (int l = 0; l < 2; ++l) {
      const int cc = c0 + l * 4;
      const int p  = p0 + cc;
      float4 val;
      if (p + 3 < TVV) {
        val = *(const float4*)(src + p);
      } else {
        val.x = (p     < TVV) ? src[p]     : 0.f;
        val.y = (p + 1 < TVV) ? src[p + 1] : 0.f;
        val.z = (p + 2 < TVV) ? src[p + 2] : 0.f;
        val.w = (p + 3 < TVV) ? src[p + 3] : 0.f;
      }
      if (PE) {
        const float* per = pe + (size_t)(k0 + r) * VV;
        val.x += per[p % VV];
        val.y += per[(p + 1) % VV];
        val.z += per[(p + 2) % VV];
        val.w += per[(p + 3) % VV];
      }
      *(float4*)&Xs[r][cc] = val;
    }
    for (int idx = tid * 4; idx < 32 * M; idx += 1024) {
      const int rr = idx / M, cw = idx % M;
      *(float4*)&Ws[rr][cw] = *(const float4*)(wT + (size_t)(k0 + rr) * M + cw);
    }
    __syncthreads();
#pragma unroll 8
    for (int k = 0; k < 32; ++k) {
      const float4 xv = *(const float4*)&Xs[k][pg * 4];
      float wv[TM];
#pragma unroll
      for (int i = 0; i < TM; ++i) wv[i] = Ws[k][og * TM + i];
#pragma unroll
      for (int i = 0; i < TM; ++i) {
        acc[i][0] = fmaf(wv[i], xv.x, acc[i][0]);
        acc[i][1] = fmaf(wv[i], xv.y, acc[i][1]);
        acc[i][2] = fmaf(wv[i], xv.z, acc[i][2]);
        acc[i][3] = fmaf(wv[i], xv.w, acc[i][3]);
      }
    }
    __syncthreads();
  }

  const size_t baseY = (size_t)n * M * TVV;
  const size_t baseR = (size_t)n * CC * TVV;   // residual is always 128-ch
  const int pcol = p0 + pg * 4;
#pragma unroll
  for (int i = 0; i < TM; ++i) {
    const int o = og * TM + i;
    const float bv = bias[o];
    if (pcol + 3 < TVV) {
      float4 st;
      st.x = acc[i][0] + bv; st.y = acc[i][1] + bv;
      st.z = acc[i][2] + bv; st.w = acc[i][3] + bv;
      if (RES) {
        const float4 rr4 = *(const float4*)(resid + baseR + (size_t)o * TVV + pcol);
        st.x += rr4.x; st.y += rr4.y; st.z += rr4.z; st.w += rr4.w;
      }
      if (LR) {
        st.x = st.x > 0.f ? st.x : 0.1f * st.x;
        st.y = st.y > 0.f ? st.y : 0.1f * st.y;
        st.z = st.z > 0.f ? st.z : 0.1f * st.z;
        st.w = st.w > 0.f ? st.w : 0.1f * st.w;
      }
      *(float4*)(Y + baseY + (size_t)o * TVV + pcol) = st;
    } else {
#pragma unroll
      for (int j = 0; j < 4; ++j) {
        const int p = pcol + j;
        if (p < TVV) {
          float v = acc[i][j] + bv;
          if (RES) v += resid[baseR + (size_t)o * TVV + p];
          if (LR)  v = v > 0.f ? v : 0.1f * v;
          Y[baseY + (size_t)o * TVV + p] = v;
        }
      }
    }
  }
}

// ---------------- attention gram partials:  M[u][v] = sum_{c,t} q k ----------
__global__ __launch_bounds__(256) void attpart_k(
    const float* __restrict__ qk, float* __restrict__ attP)
{
  __shared__ float qs[270], ks[270];
  const int ns  = blockIdx.x;          // n*2+s
  const int seg = blockIdx.y;          // 0..7, 50 t's each
  const int n = ns >> 1, s = ns & 1;
  const int tid = threadIdx.x;
  const float* qb = qk + (size_t)n * CTV + (size_t)(s * ICC) * TVV;
  const float* kb = qk + (size_t)n * CTV + (size_t)((SS + s) * ICC) * TVV;
  const int p0 = tid, p1 = tid + 256, p2 = tid + 512;
  const int u0 = p0 / VV, v0 = p0 % VV;
  const int u1 = p1 / VV, v1 = p1 % VV;
  const int u2 = p2 / VV, v2 = p2 % VV;
  float a0 = 0.f, a1 = 0.f, a2 = 0.f;
  for (int c = 0; c < ICC; ++c) {
    const float* qrow = qb + (size_t)c * TVV;
    const float* krow = kb + (size_t)c * TVV;
    for (int t0 = seg * 50; t0 < seg * 50 + 50; t0 += 10) {
      for (int idx = tid; idx < 270; idx += 256) {
        qs[idx] = qrow[t0 * VV + idx];
        ks[idx] = krow[t0 * VV + idx];
      }
      __syncthreads();
#pragma unroll
      for (int tt = 0; tt < 10; ++tt) {
        const float* qr = &qs[tt * VV];
        const float* kr = &ks[tt * VV];
        a0 = fmaf(qr[u0], kr[v0], a0);
        a1 = fmaf(qr[u1], kr[v1], a1);
        if (p2 < 729) a2 = fmaf(qr[u2], kr[v2], a2);
      }
      __syncthreads();
    }
  }
  float* dst = attP + (size_t)seg * (NN * SS * VV * VV) + (size_t)ns * (VV * VV);
  dst[p0] = a0;
  dst[p1] = a1;
  if (p2 < 729) dst[p2] = a2;
}

__global__ void attfin_k(const float* __restrict__ attP,
                         const float* __restrict__ alphas,
                         const float* __restrict__ att0,
                         float* __restrict__ att)
{
  const int idx = blockIdx.x * 256 + threadIdx.x;
  if (idx >= NN * SS * VV * VV) return;
  float m = 0.f;
#pragma unroll
  for (int g = 0; g < 8; ++g) m += attP[(size_t)g * (NN * SS * VV * VV) + idx];
  const int s  = (idx / (VV * VV)) & 1;
  const int uv = idx % (VV * VV);
  att[idx] = tanhf(m * (1.f / (ICC * TT))) * alphas[s] + att0[s * VV * VV + uv];
}

// ---------------- fused: xa = x@att ; y1 = lrelu(x + bn(out_w @ xa + b)) -----
__global__ __launch_bounds__(256, 2) void outstage_k(
    const float* __restrict__ x, const float* __restrict__ att,
    const float* __restrict__ wS, const float* __restrict__ bO,
    float* __restrict__ y1)
{
  __shared__ float Xs[CC][VV];           // x[n][:][t][:]
  __shared__ float As[SS * VV * VV];
  __shared__ float xaT[VV][260];         // [v][s*128+c], padded stride
  const int n = blockIdx.y;
  const int t = blockIdx.x;
  const int tid = threadIdx.x;
  const float* xb = x + (size_t)n * CTV + (size_t)t * VV;

  for (int idx = tid; idx < CC * VV; idx += 256)
    Xs[idx / VV][idx % VV] = xb[(size_t)(idx / VV) * TVV + (idx % VV)];
  for (int idx = tid; idx < SS * VV * VV; idx += 256)
    As[idx] = att[(size_t)n * (SS * VV * VV) + idx];
  __syncthreads();

  for (int idx = tid; idx < SS * CC * VV; idx += 256) {
    const int s = idx / (CC * VV);
    const int c = (idx / VV) % CC;
    const int v = idx % VV;
    const float* ar = &As[s * VV * VV + v];   // att[s][u][v], u-stride VV
    float a = 0.f;
#pragma unroll
    for (int u = 0; u < VV; ++u) a = fmaf(Xs[c][u], ar[u * VV], a);
    xaT[v][s * CC + c] = a;
  }
  __syncthreads();

  const int vl = tid & 31;
  const int og = tid >> 5;     // 8 groups * 16 o
  if (vl < VV) {
    const float4* xr = (const float4*)&xaT[vl][0];
    const float4* w4 = (const float4*)wS;
    float accv[16];
#pragma unroll
    for (int oi = 0; oi < 16; ++oi) accv[oi] = bO[og * 16 + oi];
#pragma unroll 4
    for (int q = 0; q < 64; ++q) {
      const float4 xv = xr[q];
#pragma unroll
      for (int oi = 0; oi < 16; ++oi) {
        const float4 w = w4[((og * 16 + oi) << 6) + q];
        accv[oi] = fmaf(w.x, xv.x, accv[oi]);
        accv[oi] = fmaf(w.y, xv.y, accv[oi]);
        accv[oi] = fmaf(w.z, xv.z, accv[oi]);
        accv[oi] = fmaf(w.w, xv.w, accv[oi]);
      }
    }
#pragma unroll
    for (int oi = 0; oi < 16; ++oi) {
      const int o = og * 16 + oi;
      float vout = accv[oi] + xb[(size_t)o * TVV + vl];
      vout = vout > 0.f ? vout : 0.1f * vout;
      y1[(size_t)n * CTV + (size_t)o * TVV + (size_t)t * VV + vl] = vout;
    }
  }
}

// ---------------- fused 3-branch TCN: dw(d=1,2,3)+bn+lrelu then pw, summed ---
__global__ __launch_bounds__(256, 2) void tcn_k(
    const float* __restrict__ yd, const float* __restrict__ dws,
    const float* __restrict__ dbs, const float* __restrict__ pws,
    const float* __restrict__ bsum, float* __restrict__ accO)
{
  __shared__ float Ys[RCC][10][VV];     // t0-3 .. t0+6
  __shared__ float Hs[RCC * 4 * VV];
  const int n  = blockIdx.y;
  const int t0 = blockIdx.x * 4;
  const int tid = threadIdx.x;
  const float* yb = yd + (size_t)n * RCC * TVV;

  for (int idx = tid; idx < RCC * 10 * VV; idx += 256) {
    const int c  = idx / (10 * VV);
    const int rr = (idx / VV) % 10;
    const int v  = idx % VV;
    const int t  = t0 - 3 + rr;
    Ys[c][rr][v] = (t >= 0 && t < TT) ? yb[(size_t)c * TVV + (size_t)t * VV + v] : 0.f;
  }
  __syncthreads();

  float accr[14];
#pragma unroll
  for (int j = 0; j < 14; ++j) accr[j] = 0.f;

  for (int i = 0; i < 3; ++i) {
    const int d = i + 1;
    for (int idx = tid; idx < RCC * 4 * VV; idx += 256) {
      const int c  = idx / (4 * VV);
      const int rr = idx % (4 * VV);
      const int t2 = rr / VV;
      const int v  = rr % VV;
      const float* w = dws + (size_t)(i * RCC + c) * 3;
      float h = dbs[i * RCC + c]
              + w[0] * Ys[c][3 + t2 - d][v]
              + w[1] * Ys[c][3 + t2][v]
              + w[2] * Ys[c][3 + t2 + d][v];
      Hs[idx] = h > 0.f ? h : 0.1f * h;
    }
    __syncthreads();
#pragma unroll
    for (int j = 0; j < 14; ++j) {
      const int idx = tid + j * 256;
      if (idx < RCC * 4 * VV) {
        const int o  = idx / (4 * VV);
        const int rr = idx % (4 * VV);
        const float* pwrow = pws + (size_t)(i * RCC + o) * RCC;
        const float* hc = &Hs[rr];
        float a = accr[j];
#pragma unroll 8
        for (int c = 0; c < RCC; ++c) a = fmaf(pwrow[c], hc[c * 4 * VV], a);
        accr[j] = a;
      }
    }
    __syncthreads();
  }
#pragma unroll
  for (int j = 0; j < 14; ++j) {
    const int idx = tid + j * 256;
    if (idx < RCC * 4 * VV) {
      const int o  = idx / (4 * VV);
      const int rr = idx % (4 * VV);
      const int t2 = rr / VV;
      const int v  = rr % VV;
      accO[(size_t)n * RCC * TVV + (size_t)o * TVV + (size_t)(t0 + t2) * VV + v]
          = accr[j] + bsum[o];
    }
  }
}

// ---------------- launch ----------------
extern "C" void kernel_launch(void* const* d_in, const int* in_sizes, int n_in,
                              void* d_out, int out_size, void* d_ws, size_t ws_size,
                              hipStream_t stream)
{
  const float* x       = (const float*)d_in[0];
  const float* in_w    = (const float*)d_in[1];
  const float* in_b    = (const float*)d_in[2];
  const float* alphas  = (const float*)d_in[3];
  const float* att0    = (const float*)d_in[4];
  const float* out_w   = (const float*)d_in[5];
  const float* out_b   = (const float*)d_in[6];
  const float* out_bn  = (const float*)d_in[7];
  const float* ff_w    = (const float*)d_in[8];
  const float* ff_b    = (const float*)d_in[9];
  const float* ff_bn   = (const float*)d_in[10];
  const float* down_w  = (const float*)d_in[11];
  const float* down_bn = (const float*)d_in[12];
  const float* dw_w    = (const float*)d_in[13];
  const float* dw_b    = (const float*)d_in[14];
  const float* bn_a    = (const float*)d_in[15];
  const float* pw_w    = (const float*)d_in[16];
  const float* bn_b    = (const float*)d_in[17];
  const float* back_w  = (const float*)d_in[18];
  const float* back_bn = (const float*)d_in[19];
  float* ws  = (float*)d_ws;
  float* out = (float*)d_out;

  // 1) fold BN, transpose weights, pos-enc table
  prep_k<<<64, 256, 0, stream>>>(in_w, out_w, out_b, out_bn, ff_w, ff_b, ff_bn,
                                 down_w, down_bn, dw_w, dw_b, bn_a, pw_w, bn_b,
                                 back_w, back_bn, ws);
  // 2) qk = in_w @ (x + pe) + in_b            -> bufA
  gemm_k<128, 128, 8, true, false, false><<<dim3(169, 32), 256, 0, stream>>>(
      x, ws + OFF_WT_IN, in_b, nullptr, ws + OFF_PE, ws + OFF_BUFA);
  // 3) attention gram partials + finalize     -> att
  attpart_k<<<dim3(64, 8), 256, 0, stream>>>(ws + OFF_BUFA, ws + OFF_ATTP);
  attfin_k<<<(NN * SS * VV * VV + 255) / 256, 256, 0, stream>>>(
      ws + OFF_ATTP, alphas, att0, ws + OFF_ATT);
  // 4) y1 = lrelu(x + bn(out_w @ (x att)))    -> d_out (used as scratch)
  outstage_k<<<dim3(400, 32), 256, 0, stream>>>(
      x, ws + OFF_ATT, ws + OFF_WS_OUT, ws + OFF_B_OUT, out);
  // 5) y2 = lrelu(x + bn(ff_w @ y1 + ff_b))   -> bufA
  gemm_k<128, 128, 8, false, true, true><<<dim3(169, 32), 256, 0, stream>>>(
      out, ws + OFF_WT_FF, ws + OFF_B_FF, x, nullptr, ws + OFF_BUFA);
  // 6) yd = lrelu(bn(down_w @ y2))            -> ws[yd]
  gemm_k<32, 128, 2, false, false, true><<<dim3(169, 32), 256, 0, stream>>>(
      ws + OFF_BUFA, ws + OFF_WT_DOWN, ws + OFF_B_DOWN, nullptr, nullptr, ws + OFF_YD);
  // 7) acc = sum_i bn(pw_i @ lrelu(bn(dw_i(yd)))) -> ws[acc]
  tcn_k<<<dim3(100, 32), 256, 0, stream>>>(
      ws + OFF_YD, ws + OFF_DWS, ws + OFF_DBS, ws + OFF_PWS, ws + OFF_BSUM, ws + OFF_ACC);
  // 8) out = lrelu(bn(back_w @ acc) + y2)     -> d_out
  gemm_k<128, 32, 8, false, true, true><<<dim3(169, 32), 256, 0, stream>>>(
      ws + OFF_ACC, ws + OFF_WT_BACK, ws + OFF_B_BACK, ws + OFF_BUFA, nullptr, out);
}

// Round 2
// 1773.656 us; speedup vs baseline: 1.6395x; 1.6395x over previous
//
#include <hip/hip_runtime.h>
#include <math.h>

// ---------------- problem constants ----------------
#define NN   32
#define CC   128
#define TT   400
#define VV   27
#define SS   2
#define ICC  32
#define RCC  32
#define TVV  (TT * VV)            // 10800
#define EPSF 1e-5f

static constexpr size_t CTV = (size_t)CC * TVV;      // 1,382,400
static constexpr size_t FSZ = (size_t)NN * CTV;      // 44,236,800
static constexpr size_t F4  = (size_t)NN * RCC * TVV;// 11,059,200

// ---------------- workspace layout (floats) ----------------
static constexpr size_t OFF_PE      = 0;        // 3456
static constexpr size_t OFF_WT_IN   = 4096;     // 16384   in_w^T [c][o]
static constexpr size_t OFF_WS_OUT  = 20480;    // 32768   out_w scaled, [c][s*128+o]
static constexpr size_t OFF_B_OUT   = 53248;    // 128
static constexpr size_t OFF_ZERO    = 53376;    // 256
static constexpr size_t OFF_WT_FF   = 53632;    // 16384   ff_w^T scaled [c][o]
static constexpr size_t OFF_B_FF    = 70016;    // 128
static constexpr size_t OFF_WT_DOWN = 70144;    // 4096    down_w^T scaled [c][o]
static constexpr size_t OFF_B_DOWN  = 74240;    // 32
static constexpr size_t OFF_DWS     = 74272;    // 288     dw_w scaled
static constexpr size_t OFF_DBS     = 74560;    // 96
static constexpr size_t OFF_PWS     = 74656;    // 3072    pw_w scaled
static constexpr size_t OFF_BSUM    = 77728;    // 32
static constexpr size_t OFF_WT_BACK = 77760;    // 4096    back_w^T scaled [k][o]
static constexpr size_t OFF_B_BACK  = 81856;    // 128
static constexpr size_t OFF_ATT     = 81984;    // 46656   [n][s][u][v]
static constexpr size_t OFF_ATTP    = 128640;   // 8*46656 partial gram
static constexpr size_t OFF_BUFA    = 501888;   // FSZ   (qk, then z0, then y2)
static constexpr size_t OFF_YD      = OFF_BUFA + FSZ;  // F4
static constexpr size_t OFF_ACC     = OFF_YD + F4;     // F4
// total ~= 66.86M floats = 267.4 MB

// ---------------- prep: pe table + transposed / BN-folded weights ----------------
__global__ void prep_k(const float* __restrict__ in_w,
                       const float* __restrict__ out_w, const float* __restrict__ out_b,
                       const float* __restrict__ out_bn,
                       const float* __restrict__ ff_w, const float* __restrict__ ff_b,
                       const float* __restrict__ ff_bn,
                       const float* __restrict__ down_w, const float* __restrict__ down_bn,
                       const float* __restrict__ dw_w, const float* __restrict__ dw_b,
                       const float* __restrict__ bn_a,
                       const float* __restrict__ pw_w, const float* __restrict__ bn_b,
                       const float* __restrict__ back_w, const float* __restrict__ back_bn,
                       float* __restrict__ ws)
{
  const int gid = blockIdx.x * blockDim.x + threadIdx.x;
  const int nth = gridDim.x * blockDim.x;
  const float rs = rsqrtf(1.f + EPSF);

  // positional encoding pe[c][v]
  for (int i = gid; i < CC * VV; i += nth) {
    const int c = i / VV, v = i % VV;
    const int h = c >> 1;
    const float div = expf((float)(2 * h) * (-logf(10000.f) / (float)CC));
    const float ang = (float)v * div;
    ws[OFF_PE + i] = (c & 1) ? cosf(ang) : sinf(ang);
  }
  // in_w^T  [c][o]
  for (int i = gid; i < CC * CC; i += nth) {
    const int c = i >> 7, o = i & 127;
    ws[OFF_WT_IN + i] = in_w[o * CC + c];
  }
  // out_w split-transposed scaled: [c][m], m = s*128+o; w = out_w[o][s*128+c]*scale[o]
  for (int i = gid; i < CC * 2 * CC; i += nth) {
    const int c = i >> 8, m = i & 255, o = m & 127, s = m >> 7;
    ws[OFF_WS_OUT + i] = out_w[o * (2 * CC) + s * CC + c] * (out_bn[o] * rs);
  }
  for (int i = gid; i < CC; i += nth) {
    const float s = out_bn[i] * rs;
    ws[OFF_B_OUT + i] = s * out_b[i] + out_bn[CC + i];
  }
  for (int i = gid; i < 256; i += nth) ws[OFF_ZERO + i] = 0.f;
  // ff
  for (int i = gid; i < CC * CC; i += nth) {
    const int c = i >> 7, o = i & 127;
    ws[OFF_WT_FF + i] = ff_w[o * CC + c] * (ff_bn[o] * rs);
  }
  for (int i = gid; i < CC; i += nth) {
    const float s = ff_bn[i] * rs;
    ws[OFF_B_FF + i] = s * ff_b[i] + ff_bn[CC + i];
  }
  // down
  for (int i = gid; i < CC * RCC; i += nth) {
    const int c = i >> 5, o = i & 31;
    ws[OFF_WT_DOWN + i] = down_w[o * CC + c] * (down_bn[o] * rs);
  }
  for (int i = gid; i < RCC; i += nth) ws[OFF_B_DOWN + i] = down_bn[RCC + i];
  // depthwise (scaled by bn_a gamma)
  for (int i = gid; i < 3 * RCC * 3; i += nth) {
    const int b = i / 96, r = i % 96, c = r / 3;
    ws[OFF_DWS + i] = dw_w[i] * (bn_a[b * 64 + c] * rs);
  }
  for (int i = gid; i < 3 * RCC; i += nth) {
    const int b = i >> 5, c = i & 31;
    ws[OFF_DBS + i] = (bn_a[b * 64 + c] * rs) * dw_b[i] + bn_a[b * 64 + 32 + c];
  }
  // pointwise (scaled by bn_b gamma)
  for (int i = gid; i < 3 * RCC * RCC; i += nth) {
    const int b = i >> 10, o = (i & 1023) >> 5;
    ws[OFF_PWS + i] = pw_w[i] * (bn_b[b * 64 + o] * rs);
  }
  for (int i = gid; i < RCC; i += nth)
    ws[OFF_BSUM + i] = bn_b[32 + i] + bn_b[96 + i] + bn_b[160 + i];
  // back
  for (int i = gid; i < RCC * CC; i += nth) {
    const int k = i >> 7, o = i & 127;
    ws[OFF_WT_BACK + i] = back_w[o * RCC + k] * (back_bn[o] * rs);
  }
  for (int i = gid; i < CC; i += nth) ws[OFF_B_BACK + i] = back_bn[CC + i];
}

// ---------------- generic 1x1-conv GEMM:  Y[n][o][p] = act(res + W^T X + b) ----
// X: [n][K][TVV], wT: [k][M]. Tile: M x 64 cols. Thread tile TM x 4.
// SPLIT: channels [0,128) -> Y, [128,256) -> Y2, both with n-stride CTV.
template<int M, int K, int TM, int NTHR, bool PE, bool RES, bool LR, bool SPLIT>
__global__ __launch_bounds__(NTHR, 4) void gemm_k(
    const float* __restrict__ X, const float* __restrict__ wT,
    const float* __restrict__ bias, const float* __restrict__ resid,
    const float* __restrict__ pe, float* __restrict__ Y, float* __restrict__ Y2)
{
  __shared__ float Xs[32][68];
  __shared__ float Ws[32][M + 4];
  const int n  = blockIdx.y;
  const int p0 = blockIdx.x * 64;
  const int tid = threadIdx.x;
  const int pg = tid & 15;            // 16 col-groups * 4
  const int og = tid >> 4;            // (NTHR/16) row-groups * TM

  float acc[TM][4];
#pragma unroll
  for (int i = 0; i < TM; ++i)
#pragma unroll
    for (int j = 0; j < 4; ++j) acc[i][j] = 0.f;

  const float* Xn = X + (size_t)n * K * TVV;

  for (int k0 = 0; k0 < K; k0 += 32) {
    // stage X tile: 32 rows x 64 cols
    for (int sl = tid; sl < 512; sl += NTHR) {
      const int r  = sl >> 4;
      const int cc = (sl & 15) * 4;
      const int p  = p0 + cc;
      const float* src = Xn + (size_t)(k0 + r) * TVV;
      float4 val;
      if (p + 3 < TVV) {
        val = *(const float4*)(src + p);
      } else {
        val.x = (p     < TVV) ? src[p]     : 0.f;
        val.y = (p + 1 < TVV) ? src[p + 1] : 0.f;
        val.z = (p + 2 < TVV) ? src[p + 2] : 0.f;
        val.w = (p + 3 < TVV) ? src[p + 3] : 0.f;
      }
      if (PE) {
        const float* per = pe + (size_t)(k0 + r) * VV;
        val.x += per[p % VV];
        val.y += per[(p + 1) % VV];
        val.z += per[(p + 2) % VV];
        val.w += per[(p + 3) % VV];
      }
      *(float4*)&Xs[r][cc] = val;
    }
    // stage W tile: 32 rows x M
    for (int idx = tid * 4; idx < 32 * M; idx += NTHR * 4) {
      const int rr = idx / M, cw = idx % M;
      *(float4*)&Ws[rr][cw] = *(const float4*)(wT + (size_t)(k0 + rr) * M + cw);
    }
    __syncthreads();
#pragma unroll 8
    for (int k = 0; k < 32; ++k) {
      const float4 xv = *(const float4*)&Xs[k][pg * 4];
      float wv[TM];
      if constexpr (TM == 8) {
        *(float4*)&wv[0] = *(const float4*)&Ws[k][og * 8];
        *(float4*)&wv[4] = *(const float4*)&Ws[k][og * 8 + 4];
      } else if constexpr (TM == 2) {
        *(float2*)&wv[0] = *(const float2*)&Ws[k][og * 2];
      } else {
#pragma unroll
        for (int i = 0; i < TM; ++i) wv[i] = Ws[k][og * TM + i];
      }
#pragma unroll
      for (int i = 0; i < TM; ++i) {
        acc[i][0] = fmaf(wv[i], xv.x, acc[i][0]);
        acc[i][1] = fmaf(wv[i], xv.y, acc[i][1]);
        acc[i][2] = fmaf(wv[i], xv.z, acc[i][2]);
        acc[i][3] = fmaf(wv[i], xv.w, acc[i][3]);
      }
    }
    __syncthreads();
  }

  const size_t baseR = (size_t)n * CTV;   // residual is always 128-ch
  const int pcol = p0 + pg * 4;
#pragma unroll
  for (int i = 0; i < TM; ++i) {
    const int o = og * TM + i;
    const float bv = bias[o];
    float* dst;
    size_t rowoff;
    if constexpr (SPLIT) {
      dst = (o < CC) ? Y : Y2;
      rowoff = (size_t)n * CTV + (size_t)(o & (CC - 1)) * TVV;
    } else {
      dst = Y;
      rowoff = (size_t)n * ((size_t)M * TVV) + (size_t)o * TVV;
    }
    if (pcol + 3 < TVV) {
      float4 st;
      st.x = acc[i][0] + bv; st.y = acc[i][1] + bv;
      st.z = acc[i][2] + bv; st.w = acc[i][3] + bv;
      if (RES) {
        const float4 rr4 = *(const float4*)(resid + baseR + (size_t)o * TVV + pcol);
        st.x += rr4.x; st.y += rr4.y; st.z += rr4.z; st.w += rr4.w;
      }
      if (LR) {
        st.x = st.x > 0.f ? st.x : 0.1f * st.x;
        st.y = st.y > 0.f ? st.y : 0.1f * st.y;
        st.z = st.z > 0.f ? st.z : 0.1f * st.z;
        st.w = st.w > 0.f ? st.w : 0.1f * st.w;
      }
      *(float4*)(dst + rowoff + pcol) = st;
    } else {
#pragma unroll
      for (int j = 0; j < 4; ++j) {
        const int p = pcol + j;
        if (p < TVV) {
          float v = acc[i][j] + bv;
          if (RES) v += resid[baseR + (size_t)o * TVV + p];
          if (LR)  v = v > 0.f ? v : 0.1f * v;
          dst[rowoff + p] = v;
        }
      }
    }
  }
}

// ---------------- attention gram partials:  M[u][v] = sum_{c,t} q k ----------
__global__ __launch_bounds__(256) void attpart_k(
    const float* __restrict__ qk, float* __restrict__ attP)
{
  __shared__ float qs[270], ks[270];
  const int ns  = blockIdx.x;          // n*2+s
  const int seg = blockIdx.y;          // 0..7, 50 t's each
  const int n = ns >> 1, s = ns & 1;
  const int tid = threadIdx.x;
  const float* qb = qk + (size_t)n * CTV + (size_t)(s * ICC) * TVV;
  const float* kb = qk + (size_t)n * CTV + (size_t)((SS + s) * ICC) * TVV;
  const int p0 = tid, p1 = tid + 256, p2 = tid + 512;
  const int u0 = p0 / VV, v0 = p0 % VV;
  const int u1 = p1 / VV, v1 = p1 % VV;
  const int u2 = p2 / VV, v2 = p2 % VV;
  float a0 = 0.f, a1 = 0.f, a2 = 0.f;
  for (int c = 0; c < ICC; ++c) {
    const float* qrow = qb + (size_t)c * TVV;
    const float* krow = kb + (size_t)c * TVV;
    for (int t0 = seg * 50; t0 < seg * 50 + 50; t0 += 10) {
      for (int idx = tid; idx < 270; idx += 256) {
        qs[idx] = qrow[t0 * VV + idx];
        ks[idx] = krow[t0 * VV + idx];
      }
      __syncthreads();
#pragma unroll
      for (int tt = 0; tt < 10; ++tt) {
        const float* qr = &qs[tt * VV];
        const float* kr = &ks[tt * VV];
        a0 = fmaf(qr[u0], kr[v0], a0);
        a1 = fmaf(qr[u1], kr[v1], a1);
        if (p2 < 729) a2 = fmaf(qr[u2], kr[v2], a2);
      }
      __syncthreads();
    }
  }
  float* dst = attP + (size_t)seg * (NN * SS * VV * VV) + (size_t)ns * (VV * VV);
  dst[p0] = a0;
  dst[p1] = a1;
  if (p2 < 729) dst[p2] = a2;
}

__global__ void attfin_k(const float* __restrict__ attP,
                         const float* __restrict__ alphas,
                         const float* __restrict__ att0,
                         float* __restrict__ att)
{
  const int idx = blockIdx.x * 256 + threadIdx.x;
  if (idx >= NN * SS * VV * VV) return;
  float m = 0.f;
#pragma unroll
  for (int g = 0; g < 8; ++g) m += attP[(size_t)g * (NN * SS * VV * VV) + idx];
  const int s  = (idx / (VV * VV)) & 1;
  const int uv = idx % (VV * VV);
  att[idx] = tanhf(m * (1.f / (ICC * TT))) * alphas[s] + att0[s * VV * VV + uv];
}

// ---------------- attention apply (after out-conv):
//   y1[n][o][t][v] = lrelu(x + bO[o] + sum_s sum_u z_s[n][o][t][u] att[n][s][u][v])
// z0 in bufA, z1 in d_out; y1 overwrites d_out in place (block-local rows).
__global__ __launch_bounds__(256, 4) void attapply_k(
    const float* __restrict__ x, const float* __restrict__ z0,
    float* __restrict__ z1y, const float* __restrict__ att,
    const float* __restrict__ bO)
{
  __shared__ float zs[256][29];        // stride 29: conflict-free column reads
  __shared__ float as[SS][VV][28];     // att padded for float4 reads
  const int n    = blockIdx.y;
  const int row0 = blockIdx.x * 256;   // flat row = o*TT + t
  const int tid  = threadIdx.x;

  for (int i = tid; i < SS * VV * VV; i += 256) {
    const int s = i / (VV * VV), uv = i % (VV * VV);
    as[s][uv / VV][uv % VV] = att[(size_t)n * (SS * VV * VV) + i];
  }
  for (int i = tid; i < SS * VV; i += 256) as[i / VV][i % VV][27] = 0.f;

  float acc[28];
#pragma unroll
  for (int j = 0; j < 28; ++j) acc[j] = 0.f;

  const size_t base = (size_t)n * CTV + (size_t)row0 * VV;

  for (int s = 0; s < SS; ++s) {
    const float* zsrc = (s == 0 ? z0 : (const float*)z1y) + base;
    __syncthreads();
    for (int e = tid; e < 256 * VV; e += 256) zs[e / VV][e % VV] = zsrc[e];
    __syncthreads();
    float zr[VV];
#pragma unroll
    for (int u = 0; u < VV; ++u) zr[u] = zs[tid][u];
#pragma unroll
    for (int vg = 0; vg < 7; ++vg) {
#pragma unroll
      for (int u = 0; u < VV; ++u) {
        const float4 a4 = *(const float4*)&as[s][u][vg * 4];
        acc[vg * 4 + 0] = fmaf(zr[u], a4.x, acc[vg * 4 + 0]);
        acc[vg * 4 + 1] = fmaf(zr[u], a4.y, acc[vg * 4 + 1]);
        acc[vg * 4 + 2] = fmaf(zr[u], a4.z, acc[vg * 4 + 2]);
        acc[vg * 4 + 3] = fmaf(zr[u], a4.w, acc[vg * 4 + 3]);
      }
    }
  }

  const int o  = (row0 + tid) / TT;
  const float bv = bO[o];
  __syncthreads();
#pragma unroll
  for (int v = 0; v < VV; ++v) zs[tid][v] = acc[v] + bv;
  __syncthreads();
  for (int e = tid; e < 256 * VV; e += 256) {
    float val = zs[e / VV][e % VV] + x[base + e];
    val = val > 0.f ? val : 0.1f * val;
    z1y[base + e] = val;
  }
}

// ---------------- fused 3-branch TCN: dw(d=1,2,3)+bn+lrelu then pw, summed ---
__global__ __launch_bounds__(256, 2) void tcn_k(
    const float* __restrict__ yd, const float* __restrict__ dws,
    const float* __restrict__ dbs, const float* __restrict__ pws,
    const float* __restrict__ bsum, float* __restrict__ accO)
{
  __shared__ float Ys[RCC][10][VV];     // t0-3 .. t0+6
  __shared__ float Hs[RCC * 4 * VV];
  const int n  = blockIdx.y;
  const int t0 = blockIdx.x * 4;
  const int tid = threadIdx.x;
  const float* yb = yd + (size_t)n * RCC * TVV;

  for (int idx = tid; idx < RCC * 10 * VV; idx += 256) {
    const int c  = idx / (10 * VV);
    const int rr = (idx / VV) % 10;
    const int v  = idx % VV;
    const int t  = t0 - 3 + rr;
    Ys[c][rr][v] = (t >= 0 && t < TT) ? yb[(size_t)c * TVV + (size_t)t * VV + v] : 0.f;
  }
  __syncthreads();

  float accr[14];
#pragma unroll
  for (int j = 0; j < 14; ++j) accr[j] = 0.f;

  for (int i = 0; i < 3; ++i) {
    const int d = i + 1;
    for (int idx = tid; idx < RCC * 4 * VV; idx += 256) {
      const int c  = idx / (4 * VV);
      const int rr = idx % (4 * VV);
      const int t2 = rr / VV;
      const int v  = rr % VV;
      const float* w = dws + (size_t)(i * RCC + c) * 3;
      float h = dbs[i * RCC + c]
              + w[0] * Ys[c][3 + t2 - d][v]
              + w[1] * Ys[c][3 + t2][v]
              + w[2] * Ys[c][3 + t2 + d][v];
      Hs[idx] = h > 0.f ? h : 0.1f * h;
    }
    __syncthreads();
#pragma unroll
    for (int j = 0; j < 14; ++j) {
      const int idx = tid + j * 256;
      if (idx < RCC * 4 * VV) {
        const int o  = idx / (4 * VV);
        const int rr = idx % (4 * VV);
        const float* pwrow = pws + (size_t)(i * RCC + o) * RCC;
        const float* hc = &Hs[rr];
        float a = accr[j];
#pragma unroll 8
        for (int c = 0; c < RCC; ++c) a = fmaf(pwrow[c], hc[c * 4 * VV], a);
        accr[j] = a;
      }
    }
    __syncthreads();
  }
#pragma unroll
  for (int j = 0; j < 14; ++j) {
    const int idx = tid + j * 256;
    if (idx < RCC * 4 * VV) {
      const int o  = idx / (4 * VV);
      const int rr = idx % (4 * VV);
      const int t2 = rr / VV;
      const int v  = rr % VV;
      accO[(size_t)n * RCC * TVV + (size_t)o * TVV + (size_t)(t0 + t2) * VV + v]
          = accr[j] + bsum[o];
    }
  }
}

// ---------------- launch ----------------
extern "C" void kernel_launch(void* const* d_in, const int* in_sizes, int n_in,
                              void* d_out, int out_size, void* d_ws, size_t ws_size,
                              hipStream_t stream)
{
  const float* x       = (const float*)d_in[0];
  const float* in_w    = (const float*)d_in[1];
  const float* in_b    = (const float*)d_in[2];
  const float* alphas  = (const float*)d_in[3];
  const float* att0    = (const float*)d_in[4];
  const float* out_w   = (const float*)d_in[5];
  const float* out_b   = (const float*)d_in[6];
  const float* out_bn  = (const float*)d_in[7];
  const float* ff_w    = (const float*)d_in[8];
  const float* ff_b    = (const float*)d_in[9];
  const float* ff_bn   = (const float*)d_in[10];
  const float* down_w  = (const float*)d_in[11];
  const float* down_bn = (const float*)d_in[12];
  const float* dw_w    = (const float*)d_in[13];
  const float* dw_b    = (const float*)d_in[14];
  const float* bn_a    = (const float*)d_in[15];
  const float* pw_w    = (const float*)d_in[16];
  const float* bn_b    = (const float*)d_in[17];
  const float* back_w  = (const float*)d_in[18];
  const float* back_bn = (const float*)d_in[19];
  float* ws  = (float*)d_ws;
  float* out = (float*)d_out;

  // 1) fold BN, transpose weights, pos-enc table
  prep_k<<<64, 256, 0, stream>>>(in_w, out_w, out_b, out_bn, ff_w, ff_b, ff_bn,
                                 down_w, down_bn, dw_w, dw_b, bn_a, pw_w, bn_b,
                                 back_w, back_bn, ws);
  // 2) qk = in_w @ (x + pe) + in_b            -> bufA
  gemm_k<128, 128, 8, 256, true, false, false, false><<<dim3(169, 32), 256, 0, stream>>>(
      x, ws + OFF_WT_IN, in_b, nullptr, ws + OFF_PE, ws + OFF_BUFA, nullptr);
  // 3) attention gram partials + finalize     -> att
  attpart_k<<<dim3(64, 8), 256, 0, stream>>>(ws + OFF_BUFA, ws + OFF_ATTP);
  attfin_k<<<(NN * SS * VV * VV + 255) / 256, 256, 0, stream>>>(
      ws + OFF_ATTP, alphas, att0, ws + OFF_ATT);
  // 4) z = [W0;W1] @ x  (out-conv BEFORE attention mix): z0 -> bufA, z1 -> d_out
  gemm_k<256, 128, 8, 512, false, false, false, true><<<dim3(169, 32), 512, 0, stream>>>(
      x, ws + OFF_WS_OUT, ws + OFF_ZERO, nullptr, nullptr, ws + OFF_BUFA, out);
  // 5) y1 = lrelu(x + bO + sum_s z_s att_s)   -> d_out (in place over z1)
  attapply_k<<<dim3(200, 32), 256, 0, stream>>>(
      x, ws + OFF_BUFA, out, ws + OFF_ATT, ws + OFF_B_OUT);
  // 6) y2 = lrelu(x + bn(ff_w @ y1 + ff_b))   -> bufA
  gemm_k<128, 128, 8, 256, false, true, true, false><<<dim3(169, 32), 256, 0, stream>>>(
      out, ws + OFF_WT_FF, ws + OFF_B_FF, x, nullptr, ws + OFF_BUFA, nullptr);
  // 7) yd = lrelu(bn(down_w @ y2))            -> ws[yd]
  gemm_k<32, 128, 2, 256, false, false, true, false><<<dim3(169, 32), 256, 0, stream>>>(
      ws + OFF_BUFA, ws + OFF_WT_DOWN, ws + OFF_B_DOWN, nullptr, nullptr, ws + OFF_YD, nullptr);
  // 8) acc = sum_i bn(pw_i @ lrelu(bn(dw_i(yd)))) -> ws[acc]
  tcn_k<<<dim3(100, 32), 256, 0, stream>>>(
      ws + OFF_YD, ws + OFF_DWS, ws + OFF_DBS, ws + OFF_PWS, ws + OFF_BSUM, ws + OFF_ACC);
  // 9) out = lrelu(bn(back_w @ acc) + y2)     -> d_out
  gemm_k<128, 32, 8, 256, false, true, true, false><<<dim3(169, 32), 256, 0, stream>>>(
      ws + OFF_ACC, ws + OFF_WT_BACK, ws + OFF_B_BACK, ws + OFF_BUFA, nullptr, out, nullptr);
}